// Round 3
// baseline (718.125 us; speedup 1.0000x reference)
//
#include <hip/hip_runtime.h>
#include <stdint.h>
#include <stddef.h>

#define M_TOK 8192
#define N_OUT 4096
#define K_IN  4096
#define R_LORA 16

// ---- 256x256 pipelined-phase GEMM geometry ----
#define BM 256
#define BN 256
#define BK 64
#define NT (K_IN / BK)          // 64 K-tiles

// fused prologue grid split (weff now 16 rows/block -> 1024 blocks)
#define WEFF_BLOCKS ((K_IN / 1024) * (N_OUT / 16))      // 4 * 256 = 1024
#define CAST_BLOCKS ((M_TOK * K_IN) / (8 * 256))        // 8 floats/thread -> 16384

typedef __bf16 bf16_t;
typedef __bf16 bf16x4 __attribute__((ext_vector_type(4)));
typedef __bf16 bf16x8 __attribute__((ext_vector_type(8)));
typedef float floatx4 __attribute__((ext_vector_type(4)));

// async global->LDS, 16B per lane. LDS dest must be wave-uniform base; HW adds lane*16.
__device__ inline void async_copy16(const bf16_t* g, bf16_t* l) {
  __builtin_amdgcn_global_load_lds(
      (__attribute__((address_space(1))) void*)(uintptr_t)(const void*)g,
      (__attribute__((address_space(3))) void*)l,
      16, 0, 0);
}

#define BAR()   __builtin_amdgcn_s_barrier()
#define VMCNT2  asm volatile("s_waitcnt vmcnt(2)" ::: "memory")
#define VMCNT0  asm volatile("s_waitcnt vmcnt(0)" ::: "memory")

// ---------------- fused prologue ----------------
// blocks [0, WEFF_BLOCKS): Weff = W + scale*B@A -> bf16. 16 rows/block (1024 blocks,
//   4 blocks/CU) to test the block-starvation hypothesis on the prologue residual.
// blocks [WEFF_BLOCKS, +CAST_BLOCKS): x fp32 -> bf16, 32B/thread read, 16B store.
__global__ __launch_bounds__(256) void prep_fused(
    const float* __restrict__ x, bf16_t* __restrict__ xb,
    const float* __restrict__ W, const float* __restrict__ lB,
    const float* __restrict__ lA, const float* __restrict__ scale_p,
    bf16_t* __restrict__ wb) {
  const int b = blockIdx.x;
  if (b < WEFF_BLOCKS) {
    const int kbase = (b & 3) * 1024 + threadIdx.x * 4;  // K_IN/1024 == 4
    const int o0    = (b >> 2) * 16;
    const float scale = *scale_p;

    float4 areg[R_LORA];
#pragma unroll
    for (int r = 0; r < R_LORA; ++r)
      areg[r] = *(const float4*)(lA + (size_t)r * K_IN + kbase);

    for (int oo = 0; oo < 16; ++oo) {
      const int o = o0 + oo;
      float4 w = *(const float4*)(W + (size_t)o * K_IN + kbase);
      float a0 = w.x, a1 = w.y, a2 = w.z, a3 = w.w;
#pragma unroll
      for (int r = 0; r < R_LORA; ++r) {
        float bb = lB[(size_t)o * R_LORA + r] * scale;  // block-uniform -> s_load
        a0 += bb * areg[r].x; a1 += bb * areg[r].y;
        a2 += bb * areg[r].z; a3 += bb * areg[r].w;
      }
      bf16x4 v;
      v[0] = (bf16_t)a0; v[1] = (bf16_t)a1; v[2] = (bf16_t)a2; v[3] = (bf16_t)a3;
      *(bf16x4*)(wb + (size_t)o * K_IN + kbase) = v;
    }
  } else {
    const size_t t = (size_t)(b - WEFF_BLOCKS) * 256 + threadIdx.x;
    const float4* xp = (const float4*)x + t * 2;
    float4 a0 = xp[0];
    float4 a1 = xp[1];
    bf16x8 v;
    v[0] = (bf16_t)a0.x; v[1] = (bf16_t)a0.y; v[2] = (bf16_t)a0.z; v[3] = (bf16_t)a0.w;
    v[4] = (bf16_t)a1.x; v[5] = (bf16_t)a1.y; v[6] = (bf16_t)a1.z; v[7] = (bf16_t)a1.w;
    *(bf16x8*)(xb + t * 8) = v;
  }
}

// ---------------- pass 2: C = A @ Bw^T + bias — pipelined 4-phase/tile ----------------
// Same geometry/layout/swizzle as round 2 (512 thr = 8 waves 2Mx4N, LDS 128 KiB,
// regions by consumption quadrant, XOR-16B-slot swizzle; conflicts measured 0).
// SCHEDULE CHANGE: each phase's ds_reads feed the NEXT phase's MFMA (double-buffered
// fragment regs a0/a1, bA/bB/bC). No explicit lgkm waits — the compiler emits exact
// counted lgkmcnt before the first consuming MFMA, so this phase's reads fly UNDER
// this phase's MFMA cluster (LDS pipe and MFMA pipe overlap; LDS-BW model ceiling
// ~62% MfmaUtil vs 38% measured for the serial read->lgkm0->MFMA structure).
// One barrier per phase (4/tile, was 8). Three vmcnt(2)/tile, each covering loads
// >=2 phases old, each immediately before a barrier ("memory" clobber also fences
// ds_read hoisting across that barrier):
//   vm@P0 covers A1(t)   for P1's a1 reads
//   vm@P2 covers A0,B0(t+1) for P3's a0/b reads
//   vm@P3 covers B1(t+1) for next P0's bB reads
__global__ __launch_bounds__(512, 2) void gemm_bt256(const bf16_t* __restrict__ A,
                                                     const bf16_t* __restrict__ Bw,
                                                     const float* __restrict__ bias,
                                                     float* __restrict__ C) {
  __shared__ bf16_t sA[2 * 2 * 128 * 64];  // 64 KB
  __shared__ bf16_t sB[2 * 2 * 128 * 64];  // 64 KB

  const int tid  = threadIdx.x;
  const int wave = tid >> 6;
  const int lane = tid & 63;
  const int lr   = lane & 15;
  const int quad = lane >> 4;
  const int wr   = wave >> 2;   // 0..1 (M)
  const int wc   = wave & 3;    // 0..3 (N)

  // bijective XCD swizzle (512 blocks, 512 % 8 == 0)
  const int bid = blockIdx.x;
  const int swz = (bid & 7) * 64 + (bid >> 3);
  const int bn  = (swz & 15) * BN;   // N index [0,16)
  const int bm  = (swz >> 4) * BM;   // M index [0,32)

  // ---- staging source pointers (per-thread, inverse-swizzled column) ----
  const int t8  = tid >> 3;                         // 0..63
  const int col = ((tid & 7) ^ (t8 & 7)) * 8;       // inverse swizzle on source
  const bf16_t* pA00 = A + (size_t)(bm +   0 + t8) * K_IN + col;  // region0, L0
  const bf16_t* pA01 = A + (size_t)(bm + 128 + t8) * K_IN + col;  // region0, L1
  const bf16_t* pA10 = A + (size_t)(bm +  64 + t8) * K_IN + col;  // region1, L0
  const bf16_t* pA11 = A + (size_t)(bm + 192 + t8) * K_IN + col;  // region1, L1
  const int brl = (t8 >> 5) * 64 + (t8 & 31);
  const bf16_t* pB00 = Bw + (size_t)(bn +   0 + brl +  0) * K_IN + col;  // nh0, L0
  const bf16_t* pB01 = Bw + (size_t)(bn + 128 + brl +  0) * K_IN + col;  // nh0, L1
  const bf16_t* pB10 = Bw + (size_t)(bn +   0 + brl + 32) * K_IN + col;  // nh1, L0
  const bf16_t* pB11 = Bw + (size_t)(bn + 128 + brl + 32) * K_IN + col;  // nh1, L1

  // ---- fragment read base pointers (swizzled slot = (ksub*4+quad) ^ (lr&7)) ----
  const char* aR0 = (const char*)sA + (size_t)(wr * 64 + lr) * 128 + ((quad) ^ (lr & 7)) * 16;
  const char* aR1 = (const char*)sA + (size_t)(wr * 64 + lr) * 128 + ((4 + quad) ^ (lr & 7)) * 16;
  const char* bR0 = (const char*)sB + (size_t)(wc * 32 + lr) * 128 + ((quad) ^ (lr & 7)) * 16;
  const char* bR1 = (const char*)sB + (size_t)(wc * 32 + lr) * 128 + ((4 + quad) ^ (lr & 7)) * 16;

  floatx4 acc[8][4];
#pragma unroll
  for (int m = 0; m < 8; ++m)
#pragma unroll
    for (int n = 0; n < 4; ++n) acc[m][n] = {0.f, 0.f, 0.f, 0.f};

  // fragment register sets (statically indexed everywhere — no scratch)
  bf16x8 a0[4][2], a1[4][2], bA[2][2], bB[2][2], bC[2][2];

#define STAGE_A0(nb) do { \
    async_copy16(pA00, sA + (nb)         + wave * 512); \
    async_copy16(pA01, sA + (nb) + 4096  + wave * 512); \
    pA00 += BK; pA01 += BK; } while (0)
#define STAGE_A1(nb) do { \
    async_copy16(pA10, sA + (nb) + 8192  + wave * 512); \
    async_copy16(pA11, sA + (nb) + 12288 + wave * 512); \
    pA10 += BK; pA11 += BK; } while (0)
#define STAGE_B0(nb) do { \
    async_copy16(pB00, sB + (nb)         + wave * 512); \
    async_copy16(pB01, sB + (nb) + 4096  + wave * 512); \
    pB00 += BK; pB01 += BK; } while (0)
#define STAGE_B1(nb) do { \
    async_copy16(pB10, sB + (nb) + 8192  + wave * 512); \
    async_copy16(pB11, sB + (nb) + 12288 + wave * 512); \
    pB10 += BK; pB11 += BK; } while (0)

#define RD_A(dst, mh, bofs) do { _Pragma("unroll") for (int mm = 0; mm < 4; ++mm) { \
    dst[mm][0] = *(const bf16x8*)(aR0 + (bofs) + (mh) * 16384 + mm * 2048); \
    dst[mm][1] = *(const bf16x8*)(aR1 + (bofs) + (mh) * 16384 + mm * 2048); } } while (0)
#define RD_B(dst, nh, bofs) do { _Pragma("unroll") for (int nn = 0; nn < 2; ++nn) { \
    dst[nn][0] = *(const bf16x8*)(bR0 + (bofs) + (nh) * 16384 + nn * 2048); \
    dst[nn][1] = *(const bf16x8*)(bR1 + (bofs) + (nh) * 16384 + nn * 2048); } } while (0)

#define MM(aset, bset, mh, nh) do { \
    __builtin_amdgcn_s_setprio(1); \
    _Pragma("unroll") for (int mm = 0; mm < 4; ++mm) \
    _Pragma("unroll") for (int nn = 0; nn < 2; ++nn) { \
      acc[(mh)*4+mm][(nh)*2+nn] = __builtin_amdgcn_mfma_f32_16x16x32_bf16( \
          aset[mm][0], bset[nn][0], acc[(mh)*4+mm][(nh)*2+nn], 0, 0, 0); \
      acc[(mh)*4+mm][(nh)*2+nn] = __builtin_amdgcn_mfma_f32_16x16x32_bf16( \
          aset[mm][1], bset[nn][1], acc[(mh)*4+mm][(nh)*2+nn], 0, 0, 0); } \
    __builtin_amdgcn_s_setprio(0); } while (0)

  // ---- prologue: stage tile 0 (buf0); vmcnt(2) completes A0,B0,B1 (A1 in flight) ----
  STAGE_A0(0); STAGE_B0(0); STAGE_B1(0); STAGE_A1(0);
  VMCNT2;
  BAR();
  RD_A(a0, 0, 0);      // a(mh0, t0)
  RD_B(bA, 0, 0);      // b(nh0, t0)

  for (int t = 0; t < NT; t += 2) {
    const bool last = (t + 2 >= NT);

    // ======== even tile t: read buf0 (byte 0), stage -> buf1 (elem 16384) ========
    // P0
    RD_B(bB, 1, 0);                 // b(nh1,t) for P1
    STAGE_A0(16384);
    MM(a0, bA, 0, 0);
    VMCNT2; BAR();                  // A1(t) landed (for P1's a1 reads)
    // P1
    RD_A(a1, 1, 0);                 // a(mh1,t) for P2
    STAGE_B0(16384);
    MM(a0, bB, 0, 1);
    BAR();
    // P2
    STAGE_B1(16384);
    MM(a1, bB, 1, 1);
    VMCNT2; BAR();                  // A0,B0(t+1) landed (for P3's reads)
    // P3
    STAGE_A1(16384);
    MM(a1, bA, 1, 0);
    RD_A(a0, 0, 32768);             // a(mh0,t+1) for next P0
    RD_B(bC, 0, 32768);             // b(nh0,t+1) for next P0
    VMCNT2; BAR();                  // B1(t+1) landed (for next P0's bB reads)

    // ======== odd tile t+1: read buf1 (byte 32768), stage -> buf0 (elem 0) ========
    // P0
    RD_B(bB, 1, 32768);
    if (!last) STAGE_A0(0);
    MM(a0, bC, 0, 0);
    if (last) { VMCNT0; } else { VMCNT2; }   // A1(t+1) landed
    BAR();
    // P1
    RD_A(a1, 1, 32768);
    if (!last) STAGE_B0(0);
    MM(a0, bB, 0, 1);
    BAR();
    // P2
    if (!last) STAGE_B1(0);
    MM(a1, bB, 1, 1);
    if (!last) VMCNT2;              // A0,B0(t+2) landed
    BAR();
    // P3
    if (!last) STAGE_A1(0);
    MM(a1, bC, 1, 0);
    if (!last) { RD_A(a0, 0, 0); RD_B(bA, 0, 0); VMCNT2; }  // B1(t+2) landed
    BAR();
  }
#undef STAGE_A0
#undef STAGE_A1
#undef STAGE_B0
#undef STAGE_B1
#undef RD_A
#undef RD_B
#undef MM

  // ---- epilogue: C row = bm + wr*128 + m*16 + quad*4 + r, col = bn + wc*64 + n*16 + lr ----
#pragma unroll
  for (int n = 0; n < 4; ++n) {
    const int colc = bn + wc * 64 + n * 16 + lr;
    const float bb = bias[colc];
#pragma unroll
    for (int m = 0; m < 8; ++m) {
      const int row0 = bm + wr * 128 + m * 16 + quad * 4;
      floatx4 v = acc[m][n];
#pragma unroll
      for (int r = 0; r < 4; ++r)
        C[(size_t)(row0 + r) * N_OUT + colc] = v[r] + bb;
    }
  }
}

// ---------------- fallback (workspace too small): fp32 path ----------------
__global__ __launch_bounds__(256) void lora_xa(const float* __restrict__ x,
                                               const float* __restrict__ lA,
                                               const float* __restrict__ scale_p,
                                               float* __restrict__ t) {
  int m = blockIdx.x;
  int r = threadIdx.x & 15;
  int kcn = threadIdx.x >> 4;
  float acc = 0.f;
  const float* xr = x + (size_t)m * K_IN + kcn * 256;
  const float* ar = lA + (size_t)r * K_IN + kcn * 256;
  for (int k = 0; k < 256; k += 4) {
    float4 xv = *(const float4*)(xr + k);
    float4 av = *(const float4*)(ar + k);
    acc += xv.x * av.x + xv.y * av.y + xv.z * av.z + xv.w * av.w;
  }
  __shared__ float s[256];
  s[threadIdx.x] = acc;
  __syncthreads();
  if (threadIdx.x < 16) {
    float v = 0.f;
    for (int i = 0; i < 16; ++i) v += s[threadIdx.x + i * 16];
    t[(size_t)m * 16 + threadIdx.x] = v * (*scale_p);
  }
}

__global__ __launch_bounds__(256) void gemm_f32_fb(const float* __restrict__ X,
                                                   const float* __restrict__ W,
                                                   const float* __restrict__ bias,
                                                   const float* __restrict__ t,
                                                   const float* __restrict__ lB,
                                                   float* __restrict__ C) {
  __shared__ float sX[64][17];
  __shared__ float sW[64][17];
  int tid = threadIdx.x;
  int tx = tid & 15, ty = tid >> 4;
  int m0 = blockIdx.y * 64, n0 = blockIdx.x * 64;
  int lrow = tid >> 2, lcol = (tid & 3) * 4;
  float acc[4][4] = {};
  for (int k0 = 0; k0 < K_IN; k0 += 16) {
    __syncthreads();
    float4 xv = *(const float4*)(X + (size_t)(m0 + lrow) * K_IN + k0 + lcol);
    float4 wv = *(const float4*)(W + (size_t)(n0 + lrow) * K_IN + k0 + lcol);
    sX[lrow][lcol + 0] = xv.x; sX[lrow][lcol + 1] = xv.y;
    sX[lrow][lcol + 2] = xv.z; sX[lrow][lcol + 3] = xv.w;
    sW[lrow][lcol + 0] = wv.x; sW[lrow][lcol + 1] = wv.y;
    sW[lrow][lcol + 2] = wv.z; sW[lrow][lcol + 3] = wv.w;
    __syncthreads();
#pragma unroll
    for (int kk = 0; kk < 16; ++kk) {
      float xr[4], wr[4];
#pragma unroll
      for (int i = 0; i < 4; ++i) { xr[i] = sX[ty * 4 + i][kk]; wr[i] = sW[tx * 4 + i][kk]; }
#pragma unroll
      for (int i = 0; i < 4; ++i)
#pragma unroll
        for (int j = 0; j < 4; ++j) acc[i][j] += xr[i] * wr[j];
    }
  }
  for (int j = 0; j < 4; ++j) {
    int n = n0 + tx * 4 + j;
    float bb = bias[n];
    for (int i = 0; i < 4; ++i) {
      int m = m0 + ty * 4 + i;
      float l = 0.f;
      for (int r = 0; r < R_LORA; ++r) l += t[(size_t)m * 16 + r] * lB[(size_t)n * 16 + r];
      C[(size_t)m * N_OUT + n] = acc[i][j] + bb + l;
    }
  }
}

extern "C" void kernel_launch(void* const* d_in, const int* in_sizes, int n_in,
                              void* d_out, int out_size, void* d_ws, size_t ws_size,
                              hipStream_t stream) {
  const float* x     = (const float*)d_in[0];
  const float* W     = (const float*)d_in[1];
  const float* bias  = (const float*)d_in[2];
  const float* lB    = (const float*)d_in[3];
  const float* lA    = (const float*)d_in[4];
  const float* scale = (const float*)d_in[5];
  float* out = (float*)d_out;

  const size_t x_bytes = (size_t)M_TOK * K_IN * sizeof(bf16_t);  // 64 MB
  const size_t w_bytes = (size_t)N_OUT * K_IN * sizeof(bf16_t);  // 32 MB

  if (ws_size >= x_bytes + w_bytes) {
    bf16_t* xb = (bf16_t*)d_ws;
    bf16_t* wb = (bf16_t*)((char*)d_ws + x_bytes);
    prep_fused<<<WEFF_BLOCKS + CAST_BLOCKS, 256, 0, stream>>>(x, xb, W, lB, lA, scale, wb);
    gemm_bt256<<<(M_TOK / BM) * (N_OUT / BN), 512, 0, stream>>>(xb, wb, bias, out);
  } else {
    float* t = (float*)d_ws;
    lora_xa<<<M_TOK, 256, 0, stream>>>(x, lA, scale, t);
    gemm_f32_fb<<<dim3(N_OUT / 64, M_TOK / 64), 256, 0, stream>>>(x, W, bias, t, lB, out);
  }
}

// Round 4
// 518.187 us; speedup vs baseline: 1.3858x; 1.3858x over previous
//
#include <hip/hip_runtime.h>
#include <stdint.h>
#include <stddef.h>

#define M_TOK 8192
#define N_OUT 4096
#define K_IN  4096
#define R_LORA 16

// ---- 256x256 4-phase/tile GEMM geometry ----
#define BM 256
#define BN 256
#define BK 64
#define NT (K_IN / BK)          // 64 K-tiles

// fused prologue grid split
#define WEFF_BLOCKS ((K_IN / 1024) * (N_OUT / 16))      // 4 * 256 = 1024
#define CAST_BLOCKS ((M_TOK * K_IN) / (8 * 256))        // 8 floats/thread -> 16384

typedef __bf16 bf16_t;
typedef __bf16 bf16x4 __attribute__((ext_vector_type(4)));
typedef __bf16 bf16x8 __attribute__((ext_vector_type(8)));
typedef float floatx4 __attribute__((ext_vector_type(4)));

// async global->LDS, 16B per lane. LDS dest must be wave-uniform base; HW adds lane*16.
__device__ inline void async_copy16(const bf16_t* g, bf16_t* l) {
  __builtin_amdgcn_global_load_lds(
      (__attribute__((address_space(1))) void*)(uintptr_t)(const void*)g,
      (__attribute__((address_space(3))) void*)l,
      16, 0, 0);
}

#define BAR()   __builtin_amdgcn_s_barrier()
#define VMCNT4  asm volatile("s_waitcnt vmcnt(4)" ::: "memory")
#define VMCNT2  asm volatile("s_waitcnt vmcnt(2)" ::: "memory")
#define VMCNT0  asm volatile("s_waitcnt vmcnt(0)" ::: "memory")

// ---------------- fused prologue (unchanged from round 3) ----------------
__global__ __launch_bounds__(256) void prep_fused(
    const float* __restrict__ x, bf16_t* __restrict__ xb,
    const float* __restrict__ W, const float* __restrict__ lB,
    const float* __restrict__ lA, const float* __restrict__ scale_p,
    bf16_t* __restrict__ wb) {
  const int b = blockIdx.x;
  if (b < WEFF_BLOCKS) {
    const int kbase = (b & 3) * 1024 + threadIdx.x * 4;  // K_IN/1024 == 4
    const int o0    = (b >> 2) * 16;
    const float scale = *scale_p;

    float4 areg[R_LORA];
#pragma unroll
    for (int r = 0; r < R_LORA; ++r)
      areg[r] = *(const float4*)(lA + (size_t)r * K_IN + kbase);

    for (int oo = 0; oo < 16; ++oo) {
      const int o = o0 + oo;
      float4 w = *(const float4*)(W + (size_t)o * K_IN + kbase);
      float a0 = w.x, a1 = w.y, a2 = w.z, a3 = w.w;
#pragma unroll
      for (int r = 0; r < R_LORA; ++r) {
        float bb = lB[(size_t)o * R_LORA + r] * scale;  // block-uniform -> s_load
        a0 += bb * areg[r].x; a1 += bb * areg[r].y;
        a2 += bb * areg[r].z; a3 += bb * areg[r].w;
      }
      bf16x4 v;
      v[0] = (bf16_t)a0; v[1] = (bf16_t)a1; v[2] = (bf16_t)a2; v[3] = (bf16_t)a3;
      *(bf16x4*)(wb + (size_t)o * K_IN + kbase) = v;
    }
  } else {
    const size_t t = (size_t)(b - WEFF_BLOCKS) * 256 + threadIdx.x;
    const float4* xp = (const float4*)x + t * 2;
    float4 a0 = xp[0];
    float4 a1 = xp[1];
    bf16x8 v;
    v[0] = (bf16_t)a0.x; v[1] = (bf16_t)a0.y; v[2] = (bf16_t)a0.z; v[3] = (bf16_t)a0.w;
    v[4] = (bf16_t)a1.x; v[5] = (bf16_t)a1.y; v[6] = (bf16_t)a1.z; v[7] = (bf16_t)a1.w;
    *(bf16x8*)(xb + t * 8) = v;
  }
}

// ---------------- pass 2: C = A @ Bw^T + bias — single-barrier 4-phase/tile ----------------
// Geometry/layout/swizzle identical to round 2 (512 thr = 8 waves 2Mx4N, LDS 128 KiB,
// regions by consumption quadrant, XOR-16B-slot swizzle; conflicts measured 0).
// SCHEDULE: each phase = [ds_reads(Q) | stage one unit of t+1 | counted vmcnt |
// setprio MFMA(Q) setprio | BAR]. No explicit lgkm waits (compiler emits exact
// counted lgkmcnt before the first consuming MFMA -> read burst overlaps MFMA
// cluster); ONE barrier per phase (4/tile, was 8 in r2; r2's LGKM0+mid-phase
// barrier forced full serial read->MFMA, MfmaUtil stuck at 38%).
// Fragment regs: a0,a1 (A by mh), bA (nh0, lives P0->P3), bB (nh1, P1->P2) —
// same live set as r2 (no r3-style 5-set pipelining; r3 spilled: WRITE_SIZE 570MB).
// vmcnt rotation (counted, never 0 in steady state; all before the phase barrier):
//   P0: stage A0(t+1); vmcnt(4) drains B1(t)      [for P1's bB reads]
//   P1: stage B0(t+1); vmcnt(4) drains A1(t)      [for P2's a1 reads]
//   P2: stage B1(t+1); no vmcnt (6 in flight)
//   P3: stage A1(t+1); vmcnt(4) drains A0,B0(t+1) [for next P0's reads]
// Cross-wave visibility: every drain happens before that phase's barrier, and the
// consuming reads are in a later phase -> stage->vmcnt->barrier->read holds.
// Stage always targets the opposite buffer from all same-tile reads (parity).
__global__ __launch_bounds__(512, 2) void gemm_bt256(const bf16_t* __restrict__ A,
                                                     const bf16_t* __restrict__ Bw,
                                                     const float* __restrict__ bias,
                                                     float* __restrict__ C) {
  __shared__ bf16_t sA[2 * 2 * 128 * 64];  // 64 KB
  __shared__ bf16_t sB[2 * 2 * 128 * 64];  // 64 KB

  const int tid  = threadIdx.x;
  const int wave = tid >> 6;
  const int lane = tid & 63;
  const int lr   = lane & 15;
  const int quad = lane >> 4;
  const int wr   = wave >> 2;   // 0..1 (M)
  const int wc   = wave & 3;    // 0..3 (N)

  // bijective XCD swizzle (512 blocks, 512 % 8 == 0)
  const int bid = blockIdx.x;
  const int swz = (bid & 7) * 64 + (bid >> 3);
  const int bn  = (swz & 15) * BN;   // N index [0,16)
  const int bm  = (swz >> 4) * BM;   // M index [0,32)

  // ---- staging source pointers (per-thread, inverse-swizzled column) ----
  const int t8  = tid >> 3;                         // 0..63
  const int col = ((tid & 7) ^ (t8 & 7)) * 8;       // inverse swizzle on source
  const bf16_t* pA00 = A + (size_t)(bm +   0 + t8) * K_IN + col;  // region0, L0
  const bf16_t* pA01 = A + (size_t)(bm + 128 + t8) * K_IN + col;  // region0, L1
  const bf16_t* pA10 = A + (size_t)(bm +  64 + t8) * K_IN + col;  // region1, L0
  const bf16_t* pA11 = A + (size_t)(bm + 192 + t8) * K_IN + col;  // region1, L1
  const int brl = (t8 >> 5) * 64 + (t8 & 31);
  const bf16_t* pB00 = Bw + (size_t)(bn +   0 + brl +  0) * K_IN + col;  // nh0, L0
  const bf16_t* pB01 = Bw + (size_t)(bn + 128 + brl +  0) * K_IN + col;  // nh0, L1
  const bf16_t* pB10 = Bw + (size_t)(bn +   0 + brl + 32) * K_IN + col;  // nh1, L0
  const bf16_t* pB11 = Bw + (size_t)(bn + 128 + brl + 32) * K_IN + col;  // nh1, L1

  // ---- fragment read base pointers (swizzled slot = (ksub*4+quad) ^ (lr&7)) ----
  const char* aR0 = (const char*)sA + (size_t)(wr * 64 + lr) * 128 + ((quad) ^ (lr & 7)) * 16;
  const char* aR1 = (const char*)sA + (size_t)(wr * 64 + lr) * 128 + ((4 + quad) ^ (lr & 7)) * 16;
  const char* bR0 = (const char*)sB + (size_t)(wc * 32 + lr) * 128 + ((quad) ^ (lr & 7)) * 16;
  const char* bR1 = (const char*)sB + (size_t)(wc * 32 + lr) * 128 + ((4 + quad) ^ (lr & 7)) * 16;

  floatx4 acc[8][4];
#pragma unroll
  for (int m = 0; m < 8; ++m)
#pragma unroll
    for (int n = 0; n < 4; ++n) acc[m][n] = {0.f, 0.f, 0.f, 0.f};

  // fragment register sets (statically indexed everywhere)
  bf16x8 a0[4][2], a1[4][2], bA[2][2], bB[2][2];

#define STAGE_A0(nb) do { \
    async_copy16(pA00, sA + (nb)         + wave * 512); \
    async_copy16(pA01, sA + (nb) + 4096  + wave * 512); \
    pA00 += BK; pA01 += BK; } while (0)
#define STAGE_A1(nb) do { \
    async_copy16(pA10, sA + (nb) + 8192  + wave * 512); \
    async_copy16(pA11, sA + (nb) + 12288 + wave * 512); \
    pA10 += BK; pA11 += BK; } while (0)
#define STAGE_B0(nb) do { \
    async_copy16(pB00, sB + (nb)         + wave * 512); \
    async_copy16(pB01, sB + (nb) + 4096  + wave * 512); \
    pB00 += BK; pB01 += BK; } while (0)
#define STAGE_B1(nb) do { \
    async_copy16(pB10, sB + (nb) + 8192  + wave * 512); \
    async_copy16(pB11, sB + (nb) + 12288 + wave * 512); \
    pB10 += BK; pB11 += BK; } while (0)

#define RD_A(dst, mh, bofs) do { _Pragma("unroll") for (int mm = 0; mm < 4; ++mm) { \
    dst[mm][0] = *(const bf16x8*)(aR0 + (bofs) + (mh) * 16384 + mm * 2048); \
    dst[mm][1] = *(const bf16x8*)(aR1 + (bofs) + (mh) * 16384 + mm * 2048); } } while (0)
#define RD_B(dst, nh, bofs) do { _Pragma("unroll") for (int nn = 0; nn < 2; ++nn) { \
    dst[nn][0] = *(const bf16x8*)(bR0 + (bofs) + (nh) * 16384 + nn * 2048); \
    dst[nn][1] = *(const bf16x8*)(bR1 + (bofs) + (nh) * 16384 + nn * 2048); } } while (0)

#define MM(aset, bset, mh, nh) do { \
    __builtin_amdgcn_s_setprio(1); \
    _Pragma("unroll") for (int mm = 0; mm < 4; ++mm) \
    _Pragma("unroll") for (int nn = 0; nn < 2; ++nn) { \
      acc[(mh)*4+mm][(nh)*2+nn] = __builtin_amdgcn_mfma_f32_16x16x32_bf16( \
          aset[mm][0], bset[nn][0], acc[(mh)*4+mm][(nh)*2+nn], 0, 0, 0); \
      acc[(mh)*4+mm][(nh)*2+nn] = __builtin_amdgcn_mfma_f32_16x16x32_bf16( \
          aset[mm][1], bset[nn][1], acc[(mh)*4+mm][(nh)*2+nn], 0, 0, 0); } \
    __builtin_amdgcn_s_setprio(0); } while (0)

// One K-tile: bo = current read-buffer byte offset, nb = next-buffer elem offset,
// ST = compile-time "not last tile".
#define TILE(bo, nb, ST) do { \
    /* P0 */ \
    RD_A(a0, 0, bo); RD_B(bA, 0, bo); \
    if (ST) { STAGE_A0(nb); VMCNT4; } else { VMCNT2; }   /* drains B1(t) */ \
    MM(a0, bA, 0, 0); \
    BAR(); \
    /* P1 */ \
    RD_B(bB, 1, bo); \
    if (ST) { STAGE_B0(nb); VMCNT4; } else { VMCNT0; }   /* drains A1(t) */ \
    MM(a0, bB, 0, 1); \
    BAR(); \
    /* P2 */ \
    RD_A(a1, 1, bo); \
    if (ST) STAGE_B1(nb);                                /* no vmcnt: 6 in flight */ \
    MM(a1, bB, 1, 1); \
    BAR(); \
    /* P3 */ \
    if (ST) { STAGE_A1(nb); VMCNT4; }                    /* drains A0,B0(t+1) */ \
    MM(a1, bA, 1, 0); \
    BAR(); \
  } while (0)

  // ---- prologue: stage tile 0 into buf0; drain A0,B0 (B1,A1 stay in flight) ----
  STAGE_A0(0); STAGE_B0(0); STAGE_B1(0); STAGE_A1(0);
  VMCNT4;
  BAR();

  for (int t = 0; t < NT - 2; t += 2) {
    TILE(0, 16384, 1);       // even tile: read buf0, stage buf1
    TILE(32768, 0, 1);       // odd tile: read buf1, stage buf0
  }
  TILE(0, 16384, 1);         // tile NT-2
  TILE(32768, 0, 0);         // tile NT-1 (no staging; drains 2 -> 0)
#undef TILE
#undef STAGE_A0
#undef STAGE_A1
#undef STAGE_B0
#undef STAGE_B1
#undef RD_A
#undef RD_B
#undef MM

  // ---- epilogue: C row = bm + wr*128 + m*16 + quad*4 + r, col = bn + wc*64 + n*16 + lr ----
#pragma unroll
  for (int n = 0; n < 4; ++n) {
    const int colc = bn + wc * 64 + n * 16 + lr;
    const float bb = bias[colc];
#pragma unroll
    for (int m = 0; m < 8; ++m) {
      const int row0 = bm + wr * 128 + m * 16 + quad * 4;
      floatx4 v = acc[m][n];
#pragma unroll
      for (int r = 0; r < 4; ++r)
        C[(size_t)(row0 + r) * N_OUT + colc] = v[r] + bb;
    }
  }
}

// ---------------- fallback (workspace too small): fp32 path ----------------
__global__ __launch_bounds__(256) void lora_xa(const float* __restrict__ x,
                                               const float* __restrict__ lA,
                                               const float* __restrict__ scale_p,
                                               float* __restrict__ t) {
  int m = blockIdx.x;
  int r = threadIdx.x & 15;
  int kcn = threadIdx.x >> 4;
  float acc = 0.f;
  const float* xr = x + (size_t)m * K_IN + kcn * 256;
  const float* ar = lA + (size_t)r * K_IN + kcn * 256;
  for (int k = 0; k < 256; k += 4) {
    float4 xv = *(const float4*)(xr + k);
    float4 av = *(const float4*)(ar + k);
    acc += xv.x * av.x + xv.y * av.y + xv.z * av.z + xv.w * av.w;
  }
  __shared__ float s[256];
  s[threadIdx.x] = acc;
  __syncthreads();
  if (threadIdx.x < 16) {
    float v = 0.f;
    for (int i = 0; i < 16; ++i) v += s[threadIdx.x + i * 16];
    t[(size_t)m * 16 + threadIdx.x] = v * (*scale_p);
  }
}

__global__ __launch_bounds__(256) void gemm_f32_fb(const float* __restrict__ X,
                                                   const float* __restrict__ W,
                                                   const float* __restrict__ bias,
                                                   const float* __restrict__ t,
                                                   const float* __restrict__ lB,
                                                   float* __restrict__ C) {
  __shared__ float sX[64][17];
  __shared__ float sW[64][17];
  int tid = threadIdx.x;
  int tx = tid & 15, ty = tid >> 4;
  int m0 = blockIdx.y * 64, n0 = blockIdx.x * 64;
  int lrow = tid >> 2, lcol = (tid & 3) * 4;
  float acc[4][4] = {};
  for (int k0 = 0; k0 < K_IN; k0 += 16) {
    __syncthreads();
    float4 xv = *(const float4*)(X + (size_t)(m0 + lrow) * K_IN + k0 + lcol);
    float4 wv = *(const float4*)(W + (size_t)(n0 + lrow) * K_IN + k0 + lcol);
    sX[lrow][lcol + 0] = xv.x; sX[lrow][lcol + 1] = xv.y;
    sX[lrow][lcol + 2] = xv.z; sX[lrow][lcol + 3] = xv.w;
    sW[lrow][lcol + 0] = wv.x; sW[lrow][lcol + 1] = wv.y;
    sW[lrow][lcol + 2] = wv.z; sW[lrow][lcol + 3] = wv.w;
    __syncthreads();
#pragma unroll
    for (int kk = 0; kk < 16; ++kk) {
      float xr[4], wr[4];
#pragma unroll
      for (int i = 0; i < 4; ++i) { xr[i] = sX[ty * 4 + i][kk]; wr[i] = sW[tx * 4 + i][kk]; }
#pragma unroll
      for (int i = 0; i < 4; ++i)
#pragma unroll
        for (int j = 0; j < 4; ++j) acc[i][j] += xr[i] * wr[j];
    }
  }
  for (int j = 0; j < 4; ++j) {
    int n = n0 + tx * 4 + j;
    float bb = bias[n];
    for (int i = 0; i < 4; ++i) {
      int m = m0 + ty * 4 + i;
      float l = 0.f;
      for (int r = 0; r < R_LORA; ++r) l += t[(size_t)m * 16 + r] * lB[(size_t)n * 16 + r];
      C[(size_t)m * N_OUT + n] = acc[i][j] + bb + l;
    }
  }
}

extern "C" void kernel_launch(void* const* d_in, const int* in_sizes, int n_in,
                              void* d_out, int out_size, void* d_ws, size_t ws_size,
                              hipStream_t stream) {
  const float* x     = (const float*)d_in[0];
  const float* W     = (const float*)d_in[1];
  const float* bias  = (const float*)d_in[2];
  const float* lB    = (const float*)d_in[3];
  const float* lA    = (const float*)d_in[4];
  const float* scale = (const float*)d_in[5];
  float* out = (float*)d_out;

  const size_t x_bytes = (size_t)M_TOK * K_IN * sizeof(bf16_t);  // 64 MB
  const size_t w_bytes = (size_t)N_OUT * K_IN * sizeof(bf16_t);  // 32 MB

  if (ws_size >= x_bytes + w_bytes) {
    bf16_t* xb = (bf16_t*)d_ws;
    bf16_t* wb = (bf16_t*)((char*)d_ws + x_bytes);
    prep_fused<<<WEFF_BLOCKS + CAST_BLOCKS, 256, 0, stream>>>(x, xb, W, lB, lA, scale, wb);
    gemm_bt256<<<(M_TOK / BM) * (N_OUT / BN), 512, 0, stream>>>(xb, wb, bias, out);
  } else {
    float* t = (float*)d_ws;
    lora_xa<<<M_TOK, 256, 0, stream>>>(x, lA, scale, t);
    gemm_f32_fb<<<dim3(N_OUT / 64, M_TOK / 64), 256, 0, stream>>>(x, W, bias, t, lB, out);
  }
}